// Round 3
// baseline (183.465 us; speedup 1.0000x reference)
//
#include <hip/hip_runtime.h>
#include <hip/hip_bf16.h>

#define BATCH 4
#define SEQ   4096
#define DIN   512
#define DOUT  64

typedef __attribute__((ext_vector_type(4))) float f32x4;
typedef __attribute__((ext_vector_type(8))) short bf16x8;   // 8 bf16 = 16B
typedef __attribute__((ext_vector_type(4))) short bf16x4;   // 4 bf16 = 8B

__device__ __forceinline__ f32x4 mfma16(bf16x8 a, bf16x8 b, f32x4 c) {
    return __builtin_amdgcn_mfma_f32_16x16x32_bf16(a, b, c, 0, 0, 0);
}
// K=16 variant: A[m][k]: m=lane&15, k=quad*4+j ; B[k][n]: n=lane&15, k=quad*4+j
__device__ __forceinline__ f32x4 mfma16k(bf16x4 a, bf16x4 b, f32x4 c) {
    return __builtin_amdgcn_mfma_f32_16x16x16bf16_1k(a, b, c, 0, 0, 0);
}

// fp32 -> bf16 round-to-nearest-even (finite inputs only)
__device__ __forceinline__ short f2bf(float f) {
    union { float f; unsigned u; } x; x.f = f;
    unsigned r = x.u + 0x7FFFu + ((x.u >> 16) & 1u);
    return (short)(r >> 16);
}

// pack two fp32 into bf16x2 (truncation) in ONE v_perm_b32
__device__ __forceinline__ unsigned pack_bf2(float lo, float hi) {
    union { float f; unsigned u; } a, b; a.f = lo; b.f = hi;
    return __builtin_amdgcn_perm(b.u, a.u, 0x07060302u);
}

// async global->LDS DMA, 16B/lane; LDS dest = wave-uniform base + lane*16.
__device__ __forceinline__ void dma16(const void* g, void* l) {
    __builtin_amdgcn_global_load_lds(
        (const __attribute__((address_space(1))) void*)g,
        (__attribute__((address_space(3))) void*)l, 16, 0, 0);
}

// Q pre-scale: 1/sqrt(64) * log2(e)  (softmax done in base 2)
#define QSCALE 0.1803368801111204f

// ---------------------------------------------------------------------------
// W convert+transpose: W[512][64] fp32 -> Wt[64][512] bf16 (coalesced reads).
// ---------------------------------------------------------------------------
__global__ __launch_bounds__(256) void wconv_kernel(
    const float* __restrict__ Wq, const float* __restrict__ Wk,
    const float* __restrict__ Wv, short* __restrict__ Wt)
{
    const int m = blockIdx.y;
    const float* W = (m == 0) ? Wq : (m == 1) ? Wk : Wv;
    const int idx = blockIdx.x * 256 + threadIdx.x;   // 0..32767
    const int k = idx >> 6;
    const int n = idx & 63;
    Wt[m * (DOUT * DIN) + n * DIN + k] = f2bf(W[idx]);
}

// ---------------------------------------------------------------------------
// QKV projection v3: LDS-free + EXPLICIT register double-buffer.
// R2 post-mortem: VGPR_Count=28 -> compiler kept ~1 load in flight, fully
// latency-serialized (48 us, worse than the DMA version's 40.6). Fix is
// structural software pipelining: prologue-load tile 0; each fully-unrolled
// kt iteration issues ALL 12 loads of tile kt+1 into the alternate register
// buffer BEFORE computing tile kt. Cross-iteration live prefetch vars force
// ~12 loads in flight per wave. All buffer indices compile-time (full
// unroll) so nothing spills to scratch. launch_bounds(256,3): VGPR cap 168;
// grid (768 blocks = 3 blk/CU) is the occupancy limit anyway.
// Per-lane addresses identical to R2 -> bit-identical output.
// ---------------------------------------------------------------------------
__global__ __launch_bounds__(256, 3) void proj_kernel(
    const float* __restrict__ Xq, const float* __restrict__ Xk, const float* __restrict__ Xv,
    const short* __restrict__ Wt,
    short* __restrict__ Qb, short* __restrict__ Kb, short* __restrict__ Vt)
{
    const int m = blockIdx.y;
    const float* X  = (m == 0) ? Xq : (m == 1) ? Xk : Xv;
    const short* Wm = Wt + m * (DOUT * DIN);

    const int tid  = threadIdx.x;
    const int wv   = tid >> 6;
    const int lane = tid & 63;
    const int quad = lane >> 4;
    const int l16  = lane & 15;
    const long waveRow = (long)blockIdx.x * 64 + wv * 16;

    // A-frag row for X; W row base (e adds 16 rows)
    const float* xg = X  + (waveRow + l16) * DIN + quad * 8;
    const short* wg = Wm + (long)l16 * DIN + quad * 8;

    f32x4 acc[4];
    #pragma unroll
    for (int e = 0; e < 4; ++e) acc[e] = (f32x4){0.f, 0.f, 0.f, 0.f};

    float4 XA[2][2], XC[2][2];      // [buf][c2]
    bf16x8 WB[2][2][4];             // [buf][c2][e]

#define LOAD_TILE(B, KT) do {                                                  \
        _Pragma("unroll")                                                      \
        for (int c2_ = 0; c2_ < 2; ++c2_) {                                    \
            XA[B][c2_] = *(const float4*)(xg + (KT) * 64 + c2_ * 32);          \
            XC[B][c2_] = *(const float4*)(xg + (KT) * 64 + c2_ * 32 + 4);      \
            _Pragma("unroll")                                                  \
            for (int e_ = 0; e_ < 4; ++e_)                                     \
                WB[B][c2_][e_] = *(const bf16x8*)(wg + (long)e_ * 16 * DIN     \
                                                  + (KT) * 64 + c2_ * 32);     \
        }                                                                      \
    } while (0)

    LOAD_TILE(0, 0);

    #pragma unroll
    for (int kt = 0; kt < 8; ++kt) {
        const int cur = kt & 1;
        if (kt < 7) LOAD_TILE(cur ^ 1, kt + 1);
        #pragma unroll
        for (int c2 = 0; c2 < 2; ++c2) {
            bf16x8 af;
            af[0] = f2bf(XA[cur][c2].x); af[1] = f2bf(XA[cur][c2].y);
            af[2] = f2bf(XA[cur][c2].z); af[3] = f2bf(XA[cur][c2].w);
            af[4] = f2bf(XC[cur][c2].x); af[5] = f2bf(XC[cur][c2].y);
            af[6] = f2bf(XC[cur][c2].z); af[7] = f2bf(XC[cur][c2].w);
            #pragma unroll
            for (int e = 0; e < 4; ++e) {
                if (m < 2) acc[e] = mfma16(af, WB[cur][c2][e], acc[e]);
                else       acc[e] = mfma16(WB[cur][c2][e], af, acc[e]);
            }
        }
    }
#undef LOAD_TILE

    if (m < 2) {
        short* O = (m == 0) ? Qb : Kb;
        const float sc = (m == 0) ? QSCALE : 1.0f;
        #pragma unroll
        for (int e = 0; e < 4; ++e)
            #pragma unroll
            for (int r = 0; r < 4; ++r)
                O[(waveRow + quad * 4 + r) * DOUT + e * 16 + l16] = f2bf(acc[e][r] * sc);
    } else {
        const long b = waveRow >> 12;
        const long s = waveRow & (SEQ - 1);
        #pragma unroll
        for (int e = 0; e < 4; ++e)
            #pragma unroll
            for (int r = 0; r < 4; ++r)
                Vt[(b * DOUT + e * 16 + quad * 4 + r) * SEQ + s + l16] = f2bf(acc[e][r]);
    }
}

// ---------------------------------------------------------------------------
// Causal flash attention v3 (unchanged — passed, 512 thr / 8 waves):
// 32-q-row / 128-key double-buffered rounds, balanced CU pairing, defer-max.
// ---------------------------------------------------------------------------
__global__ __launch_bounds__(512, 4) void flash_kernel(
    const short* __restrict__ Qb, const short* __restrict__ Kb,
    const short* __restrict__ Vt, float* __restrict__ Out)
{
    __shared__ __align__(16) char smem[2][32768];   // [buf][ K 16KB | V 16KB ]

    const int i    = blockIdx.x;                    // 512 blocks
    const int b    = (i & 7) >> 1;                  // batch -> XCD pair
    const int half = i >> 8;                        // dispatch half
    const int v    = (((i >> 3) & 31) << 1) | (i & 1);   // 0..63, unique per (b,half)
    const int t    = half ? v : (127 - v);          // heavy first; pair sums ~33 rounds

    const int tid  = threadIdx.x;
    const int wv   = tid >> 6;    // 0..7
    const int lane = tid & 63;
    const int quad = lane >> 4;
    const int l16  = lane & 15;
    const int wq   = wv >> 2;     // which q-tile
    const int wk   = wv & 3;      // which 32-key quarter of the round
    const int q0w  = t * 32 + wq * 16;

    // Q as B-frag: B[k=d][n=q]
    const short* Qp = Qb + ((long)b * SEQ + q0w + l16) * DOUT + quad * 8;
    bf16x8 qf0 = *(const bf16x8*)(Qp);
    bf16x8 qf1 = *(const bf16x8*)(Qp + 32);

    const short* Kbase  = Kb + (long)b * SEQ * DOUT;
    const short* VbaseG = Vt + (long)b * DOUT * SEQ;

    // K DMA: wave wv stages slot pair {2wv, 2wv+1} = rows kv0 + wv*16 + l16
    const short* gk = Kbase + (long)(wv * 16 + l16) * DOUT + quad * 8;
    // V DMA: wave wv stages e-rows 4wv+quad and +32; granule swizzle invariant
    const int erow = 4 * wv + quad;                 // 0..31
    const int cgr  = l16 ^ (erow & 15);
    const short* gv = VbaseG + (long)erow * SEQ + cgr * 8;

    f32x4 acc[4];
    #pragma unroll
    for (int e = 0; e < 4; ++e) acc[e] = (f32x4){0.f, 0.f, 0.f, 0.f};
    float mrow = -1e30f, lrow = 0.f;

    const int q_hi   = q0w + 15;
    const int qg     = q0w + l16;
    const int wfirst = wk * 32;        // wave's first key within a round
    const int R      = t / 4 + 1;      // 128-key rounds

#define STAGE_KV(B, KV0) do {                                         \
        char* kb_ = &smem[(B)][0];                                    \
        char* vb_ = &smem[(B)][0] + 16384;                            \
        const short* gkp_ = gk + (long)(KV0) * DOUT;                  \
        dma16(gkp_,      kb_ + (2 * wv) * 1024);                      \
        dma16(gkp_ + 32, kb_ + (2 * wv + 1) * 1024);                  \
        const short* gvp_ = gv + (KV0);                               \
        dma16(gvp_,            vb_ + (wv)     * 1024);                \
        dma16(gvp_ + 32 * SEQ, vb_ + (wv + 8) * 1024);                \
    } while (0)

    STAGE_KV(0, 0);
    __syncthreads();

    for (int r = 0; r < R; ++r) {
        const int kv0 = r * 128;
        const int cur = r & 1;
        if (r + 1 < R) STAGE_KV(cur ^ 1, kv0 + 128);

        if ((kv0 + wfirst) <= q_hi) {
            const char* kb = &smem[cur][0];
            const char* vb = &smem[cur][0] + 16384;

            // ---- scores^T: 32 keys (this wave's quarter) x 16 q ----
            f32x4 sc[2];
            #pragma unroll
            for (int kh = 0; kh < 2; ++kh) {
                const int slot = (wk * 2 + kh) * 2;
                bf16x8 k0 = *(const bf16x8*)(kb + slot * 1024 + lane * 16);
                bf16x8 k1 = *(const bf16x8*)(kb + (slot + 1) * 1024 + lane * 16);
                f32x4 z = (f32x4){0.f, 0.f, 0.f, 0.f};
                z = mfma16(k0, qf0, z);
                z = mfma16(k1, qf1, z);
                sc[kh] = z;
            }

            // ---- causal mask (key <= q); skip when round fully visible ----
            if (kv0 + wfirst + 31 > q0w) {
                #pragma unroll
                for (int kh = 0; kh < 2; ++kh)
                    #pragma unroll
                    for (int rr = 0; rr < 4; ++rr)
                        sc[kh][rr] = ((kv0 + wfirst + kh * 16 + quad * 4 + rr) <= qg)
                                   ? sc[kh][rr] : -1e30f;
            }

            // ---- online softmax (base 2), per-lane q ----
            float tm = fmaxf(fmaxf(fmaxf(sc[0][0], sc[0][1]), fmaxf(sc[0][2], sc[0][3])),
                             fmaxf(fmaxf(sc[1][0], sc[1][1]), fmaxf(sc[1][2], sc[1][3])));
            tm = fmaxf(tm, __shfl_xor(tm, 16, 64));
            tm = fmaxf(tm, __shfl_xor(tm, 32, 64));
            // defer-max: if no lane's max grew, alpha == exp2(0) == 1 exactly
            if (!__all(tm <= mrow)) {
                const float mn = fmaxf(mrow, tm);
                const float alpha = __builtin_amdgcn_exp2f(mrow - mn);
                mrow = mn;
                lrow *= alpha;
                #pragma unroll
                for (int e = 0; e < 4; ++e)
                    #pragma unroll
                    for (int rr = 0; rr < 4; ++rr) acc[e][rr] *= alpha;
            }
            float p[2][4];
            float rs0 = 0.f, rs1 = 0.f;
            #pragma unroll
            for (int kh = 0; kh < 2; ++kh)
                #pragma unroll
                for (int rr = 0; rr < 4; ++rr) {
                    p[kh][rr] = __builtin_amdgcn_exp2f(sc[kh][rr] - mrow);
                    if (kh == 0) rs0 += p[kh][rr]; else rs1 += p[kh][rr];
                }
            float rs = rs0 + rs1;
            rs += __shfl_xor(rs, 16, 64);
            rs += __shfl_xor(rs, 32, 64);
            lrow += rs;

            // ---- pack P (already B-frag for K=16 MFMA) ----
            union { unsigned u[2]; bf16x4 v; } pf[2];
            #pragma unroll
            for (int kh = 0; kh < 2; ++kh) {
                pf[kh].u[0] = pack_bf2(p[kh][0], p[kh][1]);
                pf[kh].u[1] = pack_bf2(p[kh][2], p[kh][3]);
            }

            // ---- O^T += V^T * P^T  (V from LDS, 16-granule swizzle) ----
            #pragma unroll
            for (int kh = 0; kh < 2; ++kh) {
                const int gbase = wk * 4 + kh * 2 + (quad >> 1);
                #pragma unroll
                for (int et = 0; et < 4; ++et) {
                    const int e = et * 16 + l16;
                    bf16x4 cv = *(const bf16x4*)(vb + e * 256
                                   + ((gbase ^ (e & 15)) * 16) + (quad & 1) * 8);
                    acc[et] = mfma16k(cv, pf[kh].v, acc[et]);
                }
            }
        }
        __syncthreads();   // publishes next buf; guards WAR on this buf
    }
#undef STAGE_KV

    // ---- epilogue: 4-way merge (wk quads); arrays alias the KV buffer ----
    float* s_m   = (float*)&smem[0][0];          // [8][16]
    float* s_l   = s_m + 128;                    // [8][16]
    float* s_acc = s_l + 128;                    // [8][16][65]

    if (quad == 0) { s_m[wv * 16 + l16] = mrow; s_l[wv * 16 + l16] = lrow; }
    #pragma unroll
    for (int et = 0; et < 4; ++et)
        #pragma unroll
        for (int rr = 0; rr < 4; ++rr)
            s_acc[(wv * 16 + l16) * 65 + et * 16 + quad * 4 + rr] = acc[et][rr];
    __syncthreads();

    const int col   = tid & 63;
    const int rbase = (tid >> 6) * 4;
    float* outp = Out + ((long)b * SEQ + t * 32) * DOUT;
    #pragma unroll
    for (int k = 0; k < 4; ++k) {
        const int row = rbase + k;               // 0..31
        const int w0  = (row >> 4) * 4;          // first wave of this q-tile
        const int lr  = row & 15;
        const float m0 = s_m[(w0 + 0) * 16 + lr];
        const float m1 = s_m[(w0 + 1) * 16 + lr];
        const float m2 = s_m[(w0 + 2) * 16 + lr];
        const float m3 = s_m[(w0 + 3) * 16 + lr];
        const float mM = fmaxf(fmaxf(m0, m1), fmaxf(m2, m3));
        const float a0 = __builtin_amdgcn_exp2f(m0 - mM);
        const float a1 = __builtin_amdgcn_exp2f(m1 - mM);
        const float a2 = __builtin_amdgcn_exp2f(m2 - mM);
        const float a3 = __builtin_amdgcn_exp2f(m3 - mM);
        const float li = a0 * s_l[(w0 + 0) * 16 + lr] + a1 * s_l[(w0 + 1) * 16 + lr]
                       + a2 * s_l[(w0 + 2) * 16 + lr] + a3 * s_l[(w0 + 3) * 16 + lr];
        const float o  = a0 * s_acc[((w0 + 0) * 16 + lr) * 65 + col]
                       + a1 * s_acc[((w0 + 1) * 16 + lr) * 65 + col]
                       + a2 * s_acc[((w0 + 2) * 16 + lr) * 65 + col]
                       + a3 * s_acc[((w0 + 3) * 16 + lr) * 65 + col];
        outp[row * DOUT + col] = o / li;
    }
}

extern "C" void kernel_launch(void* const* d_in, const int* in_sizes, int n_in,
                              void* d_out, int out_size, void* d_ws, size_t ws_size,
                              hipStream_t stream) {
    const float* key_in   = (const float*)d_in[0];
    const float* value_in = (const float*)d_in[1];
    const float* query_in = (const float*)d_in[2];
    const float* Wq = (const float*)d_in[3];
    const float* Wk = (const float*)d_in[4];
    const float* Wv = (const float*)d_in[5];
    float* out = (float*)d_out;

    short* Qb = (short*)d_ws;                          // 2 MB bf16 [B][S][64]  (pre-scaled)
    short* Kb = Qb + (long)BATCH * SEQ * DOUT;         // 2 MB bf16 [B][S][64]
    short* Vt = Kb + (long)BATCH * SEQ * DOUT;         // 2 MB bf16 [B][64][S]
    short* Wt = Vt + (long)BATCH * SEQ * DOUT;         // 192 KB bf16 [3][64][512]

    dim3 wgrid((DOUT * DIN) / 256, 3);
    wconv_kernel<<<wgrid, 256, 0, stream>>>(Wq, Wk, Wv, Wt);

    dim3 pgrid(BATCH * SEQ / 64, 3);
    proj_kernel<<<pgrid, 256, 0, stream>>>(query_in, key_in, value_in,
                                           Wt, Qb, Kb, Vt);

    flash_kernel<<<dim3(SEQ / 32 * BATCH), 512, 0, stream>>>(Qb, Kb, Vt, out);
}

// Round 4
// 170.162 us; speedup vs baseline: 1.0782x; 1.0782x over previous
//
#include <hip/hip_runtime.h>
#include <hip/hip_bf16.h>

#define BATCH 4
#define SEQ   4096
#define DIN   512
#define DOUT  64

typedef __attribute__((ext_vector_type(4))) float f32x4;
typedef __attribute__((ext_vector_type(8))) short bf16x8;   // 8 bf16 = 16B
typedef __attribute__((ext_vector_type(4))) short bf16x4;   // 4 bf16 = 8B

__device__ __forceinline__ f32x4 mfma16(bf16x8 a, bf16x8 b, f32x4 c) {
    return __builtin_amdgcn_mfma_f32_16x16x32_bf16(a, b, c, 0, 0, 0);
}
// K=16 variant: A[m][k]: m=lane&15, k=quad*4+j ; B[k][n]: n=lane&15, k=quad*4+j
__device__ __forceinline__ f32x4 mfma16k(bf16x4 a, bf16x4 b, f32x4 c) {
    return __builtin_amdgcn_mfma_f32_16x16x16bf16_1k(a, b, c, 0, 0, 0);
}

// fp32 -> bf16 round-to-nearest-even (finite inputs only)
__device__ __forceinline__ short f2bf(float f) {
    union { float f; unsigned u; } x; x.f = f;
    unsigned r = x.u + 0x7FFFu + ((x.u >> 16) & 1u);
    return (short)(r >> 16);
}

// pack two fp32 into bf16x2 (truncation) in ONE v_perm_b32
__device__ __forceinline__ unsigned pack_bf2(float lo, float hi) {
    union { float f; unsigned u; } a, b; a.f = lo; b.f = hi;
    return __builtin_amdgcn_perm(b.u, a.u, 0x07060302u);
}

// async global->LDS DMA, 16B/lane; LDS dest = wave-uniform base + lane*16.
__device__ __forceinline__ void dma16(const void* g, void* l) {
    __builtin_amdgcn_global_load_lds(
        (const __attribute__((address_space(1))) void*)g,
        (__attribute__((address_space(3))) void*)l, 16, 0, 0);
}

// Q pre-scale: 1/sqrt(64) * log2(e)  (softmax done in base 2)
#define QSCALE 0.1803368801111204f

// ---------------------------------------------------------------------------
// W convert+transpose: W[512][64] fp32 -> Wt[64][512] bf16 (coalesced reads).
// ---------------------------------------------------------------------------
__global__ __launch_bounds__(256) void wconv_kernel(
    const float* __restrict__ Wq, const float* __restrict__ Wk,
    const float* __restrict__ Wv, short* __restrict__ Wt)
{
    const int m = blockIdx.y;
    const float* W = (m == 0) ? Wq : (m == 1) ? Wk : Wv;
    const int idx = blockIdx.x * 256 + threadIdx.x;   // 0..32767
    const int k = idx >> 6;
    const int n = idx & 63;
    Wt[m * (DOUT * DIN) + n * DIN + k] = f2bf(W[idx]);
}

// ---------------------------------------------------------------------------
// QKV projection v4: the proven DMA-staged structure (40.6 us measured) with
// the ONE structural stall removed. R2/R3 post-mortem: plain register loads
// get sunk by the scheduler (VGPR=28 twice) -> LDS-free variants are
// latency-serialized. The DMA version keeps 6 wave-wide loads in flight but
// __syncthreads() drained vmcnt(0) every round (duty cycle ~30%). Now:
// counted vmcnt + raw s_barrier (T4, m218): per round issue 6 DMAs for tile
// kt+1, s_waitcnt vmcnt(6) waits only tile kt's DMAs, barrier, compute,
// barrier (WAR guard: W slots are cross-wave shared). Next tile's DMAs fly
// under compute. Loop fully unrolled -> waitcnt immediates are literals.
// Data path / LDS layout / per-lane addresses byte-identical to the 40.6 us
// version -> bit-identical output.
// ---------------------------------------------------------------------------
__global__ __launch_bounds__(256) void proj_kernel(
    const float* __restrict__ Xq, const float* __restrict__ Xk, const float* __restrict__ Xv,
    const short* __restrict__ Wt,
    short* __restrict__ Qb, short* __restrict__ Kb, short* __restrict__ Vt)
{
    __shared__ __align__(16) char smem[2][24576];   // [buf][ X 16KB | W 8KB ]

    const int m = blockIdx.y;
    const float* X  = (m == 0) ? Xq : (m == 1) ? Xk : Xv;
    const short* Wm = Wt + m * (DOUT * DIN);

    const int tid  = threadIdx.x;
    const int wv   = tid >> 6;
    const int lane = tid & 63;
    const int quad = lane >> 4;
    const int l16  = lane & 15;
    const long waveRow = (long)blockIdx.x * 64 + wv * 16;

    const float* xg = X  + (waveRow + l16) * DIN + quad * 8;
    const short* wg = Wm + (long)(wv * 16 + l16) * DIN + quad * 8;

    f32x4 acc[4];
    #pragma unroll
    for (int e = 0; e < 4; ++e) acc[e] = (f32x4){0.f, 0.f, 0.f, 0.f};

#define STAGE_PROJ(B) do {                                   \
        char* xb_ = &smem[(B)][0] + wv * 4096;               \
        char* wb_ = &smem[(B)][0] + 16384 + wv * 2048;       \
        dma16(xg,      xb_);                                 \
        dma16(xg + 4,  xb_ + 1024);                          \
        dma16(xg + 32, xb_ + 2048);                          \
        dma16(xg + 36, xb_ + 3072);                          \
        dma16(wg,      wb_);                                 \
        dma16(wg + 32, wb_ + 1024);                          \
    } while (0)

    STAGE_PROJ(0);
    xg += 64; wg += 64;

    #pragma unroll
    for (int kt = 0; kt < 8; ++kt) {
        const int cur = kt & 1;
        if (kt < 7) {
            if (cur) { STAGE_PROJ(0); } else { STAGE_PROJ(1); }
            xg += 64; wg += 64;
            __builtin_amdgcn_sched_barrier(0);
            asm volatile("s_waitcnt vmcnt(6)" ::: "memory");   // tile kt's 6 DMAs done
            __builtin_amdgcn_sched_barrier(0);
        } else {
            __builtin_amdgcn_sched_barrier(0);
            asm volatile("s_waitcnt vmcnt(0)" ::: "memory");   // last tile: drain
            __builtin_amdgcn_sched_barrier(0);
        }
        __builtin_amdgcn_s_barrier();          // buf[cur] fully published

        const char* xb = &smem[cur][0] + wv * 4096;
        const char* wb = &smem[cur][0] + 16384;
        #pragma unroll
        for (int c2 = 0; c2 < 2; ++c2) {
            float4 xa = *(const float4*)(xb + c2 * 2048 + lane * 16);
            float4 xc = *(const float4*)(xb + c2 * 2048 + 1024 + lane * 16);
            bf16x8 af;
            af[0] = f2bf(xa.x); af[1] = f2bf(xa.y); af[2] = f2bf(xa.z); af[3] = f2bf(xa.w);
            af[4] = f2bf(xc.x); af[5] = f2bf(xc.y); af[6] = f2bf(xc.z); af[7] = f2bf(xc.w);
            #pragma unroll
            for (int e = 0; e < 4; ++e) {
                bf16x8 bf = *(const bf16x8*)(wb + (e * 2 + c2) * 1024 + lane * 16);
                if (m < 2) acc[e] = mfma16(af, bf, acc[e]);
                else       acc[e] = mfma16(bf, af, acc[e]);
            }
        }
        if (kt < 7) __builtin_amdgcn_s_barrier();   // WAR: shared W slots reread done
    }
#undef STAGE_PROJ

    if (m < 2) {
        short* O = (m == 0) ? Qb : Kb;
        const float sc = (m == 0) ? QSCALE : 1.0f;
        #pragma unroll
        for (int e = 0; e < 4; ++e)
            #pragma unroll
            for (int r = 0; r < 4; ++r)
                O[(waveRow + quad * 4 + r) * DOUT + e * 16 + l16] = f2bf(acc[e][r] * sc);
    } else {
        const long b = waveRow >> 12;
        const long s = waveRow & (SEQ - 1);
        #pragma unroll
        for (int e = 0; e < 4; ++e)
            #pragma unroll
            for (int r = 0; r < 4; ++r)
                Vt[(b * DOUT + e * 16 + quad * 4 + r) * SEQ + s + l16] = f2bf(acc[e][r]);
    }
}

// ---------------------------------------------------------------------------
// Causal flash attention v3 (unchanged — passed, 512 thr / 8 waves):
// 32-q-row / 128-key double-buffered rounds, balanced CU pairing, defer-max.
// ---------------------------------------------------------------------------
__global__ __launch_bounds__(512, 4) void flash_kernel(
    const short* __restrict__ Qb, const short* __restrict__ Kb,
    const short* __restrict__ Vt, float* __restrict__ Out)
{
    __shared__ __align__(16) char smem[2][32768];   // [buf][ K 16KB | V 16KB ]

    const int i    = blockIdx.x;                    // 512 blocks
    const int b    = (i & 7) >> 1;                  // batch -> XCD pair
    const int half = i >> 8;                        // dispatch half
    const int v    = (((i >> 3) & 31) << 1) | (i & 1);   // 0..63, unique per (b,half)
    const int t    = half ? v : (127 - v);          // heavy first; pair sums ~33 rounds

    const int tid  = threadIdx.x;
    const int wv   = tid >> 6;    // 0..7
    const int lane = tid & 63;
    const int quad = lane >> 4;
    const int l16  = lane & 15;
    const int wq   = wv >> 2;     // which q-tile
    const int wk   = wv & 3;      // which 32-key quarter of the round
    const int q0w  = t * 32 + wq * 16;

    // Q as B-frag: B[k=d][n=q]
    const short* Qp = Qb + ((long)b * SEQ + q0w + l16) * DOUT + quad * 8;
    bf16x8 qf0 = *(const bf16x8*)(Qp);
    bf16x8 qf1 = *(const bf16x8*)(Qp + 32);

    const short* Kbase  = Kb + (long)b * SEQ * DOUT;
    const short* VbaseG = Vt + (long)b * DOUT * SEQ;

    // K DMA: wave wv stages slot pair {2wv, 2wv+1} = rows kv0 + wv*16 + l16
    const short* gk = Kbase + (long)(wv * 16 + l16) * DOUT + quad * 8;
    // V DMA: wave wv stages e-rows 4wv+quad and +32; granule swizzle invariant
    const int erow = 4 * wv + quad;                 // 0..31
    const int cgr  = l16 ^ (erow & 15);
    const short* gv = VbaseG + (long)erow * SEQ + cgr * 8;

    f32x4 acc[4];
    #pragma unroll
    for (int e = 0; e < 4; ++e) acc[e] = (f32x4){0.f, 0.f, 0.f, 0.f};
    float mrow = -1e30f, lrow = 0.f;

    const int q_hi   = q0w + 15;
    const int qg     = q0w + l16;
    const int wfirst = wk * 32;        // wave's first key within a round
    const int R      = t / 4 + 1;      // 128-key rounds

#define STAGE_KV(B, KV0) do {                                         \
        char* kb_ = &smem[(B)][0];                                    \
        char* vb_ = &smem[(B)][0] + 16384;                            \
        const short* gkp_ = gk + (long)(KV0) * DOUT;                  \
        dma16(gkp_,      kb_ + (2 * wv) * 1024);                      \
        dma16(gkp_ + 32, kb_ + (2 * wv + 1) * 1024);                  \
        const short* gvp_ = gv + (KV0);                               \
        dma16(gvp_,            vb_ + (wv)     * 1024);                \
        dma16(gvp_ + 32 * SEQ, vb_ + (wv + 8) * 1024);                \
    } while (0)

    STAGE_KV(0, 0);
    __syncthreads();

    for (int r = 0; r < R; ++r) {
        const int kv0 = r * 128;
        const int cur = r & 1;
        if (r + 1 < R) STAGE_KV(cur ^ 1, kv0 + 128);

        if ((kv0 + wfirst) <= q_hi) {
            const char* kb = &smem[cur][0];
            const char* vb = &smem[cur][0] + 16384;

            // ---- scores^T: 32 keys (this wave's quarter) x 16 q ----
            f32x4 sc[2];
            #pragma unroll
            for (int kh = 0; kh < 2; ++kh) {
                const int slot = (wk * 2 + kh) * 2;
                bf16x8 k0 = *(const bf16x8*)(kb + slot * 1024 + lane * 16);
                bf16x8 k1 = *(const bf16x8*)(kb + (slot + 1) * 1024 + lane * 16);
                f32x4 z = (f32x4){0.f, 0.f, 0.f, 0.f};
                z = mfma16(k0, qf0, z);
                z = mfma16(k1, qf1, z);
                sc[kh] = z;
            }

            // ---- causal mask (key <= q); skip when round fully visible ----
            if (kv0 + wfirst + 31 > q0w) {
                #pragma unroll
                for (int kh = 0; kh < 2; ++kh)
                    #pragma unroll
                    for (int rr = 0; rr < 4; ++rr)
                        sc[kh][rr] = ((kv0 + wfirst + kh * 16 + quad * 4 + rr) <= qg)
                                   ? sc[kh][rr] : -1e30f;
            }

            // ---- online softmax (base 2), per-lane q ----
            float tm = fmaxf(fmaxf(fmaxf(sc[0][0], sc[0][1]), fmaxf(sc[0][2], sc[0][3])),
                             fmaxf(fmaxf(sc[1][0], sc[1][1]), fmaxf(sc[1][2], sc[1][3])));
            tm = fmaxf(tm, __shfl_xor(tm, 16, 64));
            tm = fmaxf(tm, __shfl_xor(tm, 32, 64));
            // defer-max: if no lane's max grew, alpha == exp2(0) == 1 exactly
            if (!__all(tm <= mrow)) {
                const float mn = fmaxf(mrow, tm);
                const float alpha = __builtin_amdgcn_exp2f(mrow - mn);
                mrow = mn;
                lrow *= alpha;
                #pragma unroll
                for (int e = 0; e < 4; ++e)
                    #pragma unroll
                    for (int rr = 0; rr < 4; ++rr) acc[e][rr] *= alpha;
            }
            float p[2][4];
            float rs0 = 0.f, rs1 = 0.f;
            #pragma unroll
            for (int kh = 0; kh < 2; ++kh)
                #pragma unroll
                for (int rr = 0; rr < 4; ++rr) {
                    p[kh][rr] = __builtin_amdgcn_exp2f(sc[kh][rr] - mrow);
                    if (kh == 0) rs0 += p[kh][rr]; else rs1 += p[kh][rr];
                }
            float rs = rs0 + rs1;
            rs += __shfl_xor(rs, 16, 64);
            rs += __shfl_xor(rs, 32, 64);
            lrow += rs;

            // ---- pack P (already B-frag for K=16 MFMA) ----
            union { unsigned u[2]; bf16x4 v; } pf[2];
            #pragma unroll
            for (int kh = 0; kh < 2; ++kh) {
                pf[kh].u[0] = pack_bf2(p[kh][0], p[kh][1]);
                pf[kh].u[1] = pack_bf2(p[kh][2], p[kh][3]);
            }

            // ---- O^T += V^T * P^T  (V from LDS, 16-granule swizzle) ----
            #pragma unroll
            for (int kh = 0; kh < 2; ++kh) {
                const int gbase = wk * 4 + kh * 2 + (quad >> 1);
                #pragma unroll
                for (int et = 0; et < 4; ++et) {
                    const int e = et * 16 + l16;
                    bf16x4 cv = *(const bf16x4*)(vb + e * 256
                                   + ((gbase ^ (e & 15)) * 16) + (quad & 1) * 8);
                    acc[et] = mfma16k(cv, pf[kh].v, acc[et]);
                }
            }
        }
        __syncthreads();   // publishes next buf; guards WAR on this buf
    }
#undef STAGE_KV

    // ---- epilogue: 4-way merge (wk quads); arrays alias the KV buffer ----
    float* s_m   = (float*)&smem[0][0];          // [8][16]
    float* s_l   = s_m + 128;                    // [8][16]
    float* s_acc = s_l + 128;                    // [8][16][65]

    if (quad == 0) { s_m[wv * 16 + l16] = mrow; s_l[wv * 16 + l16] = lrow; }
    #pragma unroll
    for (int et = 0; et < 4; ++et)
        #pragma unroll
        for (int rr = 0; rr < 4; ++rr)
            s_acc[(wv * 16 + l16) * 65 + et * 16 + quad * 4 + rr] = acc[et][rr];
    __syncthreads();

    const int col   = tid & 63;
    const int rbase = (tid >> 6) * 4;
    float* outp = Out + ((long)b * SEQ + t * 32) * DOUT;
    #pragma unroll
    for (int k = 0; k < 4; ++k) {
        const int row = rbase + k;               // 0..31
        const int w0  = (row >> 4) * 4;          // first wave of this q-tile
        const int lr  = row & 15;
        const float m0 = s_m[(w0 + 0) * 16 + lr];
        const float m1 = s_m[(w0 + 1) * 16 + lr];
        const float m2 = s_m[(w0 + 2) * 16 + lr];
        const float m3 = s_m[(w0 + 3) * 16 + lr];
        const float mM = fmaxf(fmaxf(m0, m1), fmaxf(m2, m3));
        const float a0 = __builtin_amdgcn_exp2f(m0 - mM);
        const float a1 = __builtin_amdgcn_exp2f(m1 - mM);
        const float a2 = __builtin_amdgcn_exp2f(m2 - mM);
        const float a3 = __builtin_amdgcn_exp2f(m3 - mM);
        const float li = a0 * s_l[(w0 + 0) * 16 + lr] + a1 * s_l[(w0 + 1) * 16 + lr]
                       + a2 * s_l[(w0 + 2) * 16 + lr] + a3 * s_l[(w0 + 3) * 16 + lr];
        const float o  = a0 * s_acc[((w0 + 0) * 16 + lr) * 65 + col]
                       + a1 * s_acc[((w0 + 1) * 16 + lr) * 65 + col]
                       + a2 * s_acc[((w0 + 2) * 16 + lr) * 65 + col]
                       + a3 * s_acc[((w0 + 3) * 16 + lr) * 65 + col];
        outp[row * DOUT + col] = o / li;
    }
}

extern "C" void kernel_launch(void* const* d_in, const int* in_sizes, int n_in,
                              void* d_out, int out_size, void* d_ws, size_t ws_size,
                              hipStream_t stream) {
    const float* key_in   = (const float*)d_in[0];
    const float* value_in = (const float*)d_in[1];
    const float* query_in = (const float*)d_in[2];
    const float* Wq = (const float*)d_in[3];
    const float* Wk = (const float*)d_in[4];
    const float* Wv = (const float*)d_in[5];
    float* out = (float*)d_out;

    short* Qb = (short*)d_ws;                          // 2 MB bf16 [B][S][64]  (pre-scaled)
    short* Kb = Qb + (long)BATCH * SEQ * DOUT;         // 2 MB bf16 [B][S][64]
    short* Vt = Kb + (long)BATCH * SEQ * DOUT;         // 2 MB bf16 [B][64][S]
    short* Wt = Vt + (long)BATCH * SEQ * DOUT;         // 192 KB bf16 [3][64][512]

    dim3 wgrid((DOUT * DIN) / 256, 3);
    wconv_kernel<<<wgrid, 256, 0, stream>>>(Wq, Wk, Wv, Wt);

    dim3 pgrid(BATCH * SEQ / 64, 3);
    proj_kernel<<<pgrid, 256, 0, stream>>>(query_in, key_in, value_in,
                                           Wt, Qb, Kb, Vt);

    flash_kernel<<<dim3(SEQ / 32 * BATCH), 512, 0, stream>>>(Qb, Kb, Vt, out);
}

// Round 5
// 163.874 us; speedup vs baseline: 1.1196x; 1.0384x over previous
//
#include <hip/hip_runtime.h>
#include <hip/hip_bf16.h>

#define BATCH 4
#define SEQ   4096
#define DIN   512
#define DOUT  64

typedef __attribute__((ext_vector_type(4))) float f32x4;
typedef __attribute__((ext_vector_type(8))) short bf16x8;   // 8 bf16 = 16B
typedef __attribute__((ext_vector_type(4))) short bf16x4;   // 4 bf16 = 8B

__device__ __forceinline__ f32x4 mfma16(bf16x8 a, bf16x8 b, f32x4 c) {
    return __builtin_amdgcn_mfma_f32_16x16x32_bf16(a, b, c, 0, 0, 0);
}
// K=16 variant: A[m][k]: m=lane&15, k=quad*4+j ; B[k][n]: n=lane&15, k=quad*4+j
__device__ __forceinline__ f32x4 mfma16k(bf16x4 a, bf16x4 b, f32x4 c) {
    return __builtin_amdgcn_mfma_f32_16x16x16bf16_1k(a, b, c, 0, 0, 0);
}

// fp32 -> bf16 round-to-nearest-even (finite inputs only)
__device__ __forceinline__ short f2bf(float f) {
    union { float f; unsigned u; } x; x.f = f;
    unsigned r = x.u + 0x7FFFu + ((x.u >> 16) & 1u);
    return (short)(r >> 16);
}

// pack two fp32 into bf16x2 (truncation) in ONE v_perm_b32
__device__ __forceinline__ unsigned pack_bf2(float lo, float hi) {
    union { float f; unsigned u; } a, b; a.f = lo; b.f = hi;
    return __builtin_amdgcn_perm(b.u, a.u, 0x07060302u);
}

// async global->LDS DMA, 16B/lane; LDS dest = wave-uniform base + lane*16.
__device__ __forceinline__ void dma16(const void* g, void* l) {
    __builtin_amdgcn_global_load_lds(
        (const __attribute__((address_space(1))) void*)g,
        (__attribute__((address_space(3))) void*)l, 16, 0, 0);
}

// Q pre-scale: 1/sqrt(64) * log2(e)  (softmax done in base 2)
#define QSCALE 0.1803368801111204f

// ---------------------------------------------------------------------------
// W convert+transpose: W[512][64] fp32 -> Wt[64][512] bf16 (coalesced reads).
// ---------------------------------------------------------------------------
__global__ __launch_bounds__(256) void wconv_kernel(
    const float* __restrict__ Wq, const float* __restrict__ Wk,
    const float* __restrict__ Wv, short* __restrict__ Wt)
{
    const int m = blockIdx.y;
    const float* W = (m == 0) ? Wq : (m == 1) ? Wk : Wv;
    const int idx = blockIdx.x * 256 + threadIdx.x;   // 0..32767
    const int k = idx >> 6;
    const int n = idx & 63;
    Wt[m * (DOUT * DIN) + n * DIN + k] = f2bf(W[idx]);
}

// ---------------------------------------------------------------------------
// QKV projection v5: DMA staging with COALESCED lane mapping.
// R4 post-mortem: counted vmcnt was NEUTRAL (proj ~40.9 us across drain,
// counted, and register variants) -> stall is DMA service rate, not sync.
// Root cause: old lane map (lane = quad*16+l16, addr = row(l16)*2KB +
// quad*32B) put CONSECUTIVE LANES 2KB APART -> each global_load_lds issued
// 64 isolated 16B requests (quarter-cachelines, zero coalescing). W same
// (1KB lane stride). Now: row = lane>>2, chunk = (lane&3)*16B -> 4
// consecutive lanes form one full 64B cacheline request; 16 line-requests
// per instruction instead of 64 subline requests. Same bytes, same 6 DMAs
// per stage (vmcnt(6) unchanged), same per-value results (fragment reads
// re-derived for the [j][row][chunk] layout; af[] gets identical floats).
// Read-side bank conflicts (~4-8 way on ds_read_b128) cost ~300cy/round --
// noise against the 12k-cycle rounds this attacks.
// ---------------------------------------------------------------------------
__global__ __launch_bounds__(256) void proj_kernel(
    const float* __restrict__ Xq, const float* __restrict__ Xk, const float* __restrict__ Xv,
    const short* __restrict__ Wt,
    short* __restrict__ Qb, short* __restrict__ Kb, short* __restrict__ Vt)
{
    __shared__ __align__(16) char smem[2][24576];   // [buf][ X 16KB | W 8KB ]

    const int m = blockIdx.y;
    const float* X  = (m == 0) ? Xq : (m == 1) ? Xk : Xv;
    const short* Wm = Wt + m * (DOUT * DIN);

    const int tid  = threadIdx.x;
    const int wv   = tid >> 6;
    const int lane = tid & 63;
    const int quad = lane >> 4;
    const int l16  = lane & 15;
    const long waveRow = (long)blockIdx.x * 64 + wv * 16;

    // DMA source bases: consecutive lanes contiguous (64B line per 4 lanes)
    const float* xg = X  + (waveRow + (lane >> 2)) * DIN + (lane & 3) * 4;
    const short* wg = Wm + (long)(wv * 16 + (lane >> 2)) * DIN + (lane & 3) * 8;

    f32x4 acc[4];
    #pragma unroll
    for (int e = 0; e < 4; ++e) acc[e] = (f32x4){0.f, 0.f, 0.f, 0.f};

    // X slice layout per wave (4KB): [j:4][row:16][chunk:4 x 16B]
    //   instr j covers floats [j*16, j*16+16) of each of the wave's 16 rows
    // W slice layout per wave (2KB): [j:2][row:16][chunk:4 x 16B]
    //   instr j covers shorts [j*32, j*32+32) of rows wv*16..+16
#define STAGE_PROJ(B) do {                                   \
        char* xb_ = &smem[(B)][0] + wv * 4096;               \
        char* wb_ = &smem[(B)][0] + 16384 + wv * 2048;       \
        dma16(xg,      xb_);                                 \
        dma16(xg + 16, xb_ + 1024);                          \
        dma16(xg + 32, xb_ + 2048);                          \
        dma16(xg + 48, xb_ + 3072);                          \
        dma16(wg,      wb_);                                 \
        dma16(wg + 32, wb_ + 1024);                          \
    } while (0)

    STAGE_PROJ(0);
    xg += 64; wg += 64;

    #pragma unroll
    for (int kt = 0; kt < 8; ++kt) {
        const int cur = kt & 1;
        if (kt < 7) {
            if (cur) { STAGE_PROJ(0); } else { STAGE_PROJ(1); }
            xg += 64; wg += 64;
            __builtin_amdgcn_sched_barrier(0);
            asm volatile("s_waitcnt vmcnt(6)" ::: "memory");   // tile kt's 6 DMAs done
            __builtin_amdgcn_sched_barrier(0);
        } else {
            __builtin_amdgcn_sched_barrier(0);
            asm volatile("s_waitcnt vmcnt(0)" ::: "memory");   // last tile: drain
            __builtin_amdgcn_sched_barrier(0);
        }
        __builtin_amdgcn_s_barrier();          // buf[cur] fully published

        const char* xb = &smem[cur][0] + wv * 4096;
        const char* wb = &smem[cur][0] + 16384;
        #pragma unroll
        for (int c2 = 0; c2 < 2; ++c2) {
            // floats f = c2*32 + quad*8 .. of row l16:
            //   j = c2*2 + (quad>>1), within-row 64B chunk offset (quad&1)*32
            const char* xp = xb + (c2 * 2 + (quad >> 1)) * 1024
                                + l16 * 64 + (quad & 1) * 32;
            float4 xa = *(const float4*)(xp);
            float4 xc = *(const float4*)(xp + 16);
            bf16x8 af;
            af[0] = f2bf(xa.x); af[1] = f2bf(xa.y); af[2] = f2bf(xa.z); af[3] = f2bf(xa.w);
            af[4] = f2bf(xc.x); af[5] = f2bf(xc.y); af[6] = f2bf(xc.z); af[7] = f2bf(xc.w);
            #pragma unroll
            for (int e = 0; e < 4; ++e) {
                // W[n = e*16 + l16][shorts c2*32 + quad*8 ..+8]:
                //   staged by wave e -> slice e*2048, j = c2, chunk = quad
                bf16x8 bf = *(const bf16x8*)(wb + e * 2048 + c2 * 1024
                                                + l16 * 64 + quad * 16);
                if (m < 2) acc[e] = mfma16(af, bf, acc[e]);
                else       acc[e] = mfma16(bf, af, acc[e]);
            }
        }
        if (kt < 7) __builtin_amdgcn_s_barrier();   // WAR: shared W slots reread done
    }
#undef STAGE_PROJ

    if (m < 2) {
        short* O = (m == 0) ? Qb : Kb;
        const float sc = (m == 0) ? QSCALE : 1.0f;
        #pragma unroll
        for (int e = 0; e < 4; ++e)
            #pragma unroll
            for (int r = 0; r < 4; ++r)
                O[(waveRow + quad * 4 + r) * DOUT + e * 16 + l16] = f2bf(acc[e][r] * sc);
    } else {
        const long b = waveRow >> 12;
        const long s = waveRow & (SEQ - 1);
        #pragma unroll
        for (int e = 0; e < 4; ++e)
            #pragma unroll
            for (int r = 0; r < 4; ++r)
                Vt[(b * DOUT + e * 16 + quad * 4 + r) * SEQ + s + l16] = f2bf(acc[e][r]);
    }
}

// ---------------------------------------------------------------------------
// Causal flash attention v3 (unchanged — passed, 512 thr / 8 waves):
// 32-q-row / 128-key double-buffered rounds, balanced CU pairing, defer-max.
// ---------------------------------------------------------------------------
__global__ __launch_bounds__(512, 4) void flash_kernel(
    const short* __restrict__ Qb, const short* __restrict__ Kb,
    const short* __restrict__ Vt, float* __restrict__ Out)
{
    __shared__ __align__(16) char smem[2][32768];   // [buf][ K 16KB | V 16KB ]

    const int i    = blockIdx.x;                    // 512 blocks
    const int b    = (i & 7) >> 1;                  // batch -> XCD pair
    const int half = i >> 8;                        // dispatch half
    const int v    = (((i >> 3) & 31) << 1) | (i & 1);   // 0..63, unique per (b,half)
    const int t    = half ? v : (127 - v);          // heavy first; pair sums ~33 rounds

    const int tid  = threadIdx.x;
    const int wv   = tid >> 6;    // 0..7
    const int lane = tid & 63;
    const int quad = lane >> 4;
    const int l16  = lane & 15;
    const int wq   = wv >> 2;     // which q-tile
    const int wk   = wv & 3;      // which 32-key quarter of the round
    const int q0w  = t * 32 + wq * 16;

    // Q as B-frag: B[k=d][n=q]
    const short* Qp = Qb + ((long)b * SEQ + q0w + l16) * DOUT + quad * 8;
    bf16x8 qf0 = *(const bf16x8*)(Qp);
    bf16x8 qf1 = *(const bf16x8*)(Qp + 32);

    const short* Kbase  = Kb + (long)b * SEQ * DOUT;
    const short* VbaseG = Vt + (long)b * DOUT * SEQ;

    // K DMA: wave wv stages slot pair {2wv, 2wv+1} = rows kv0 + wv*16 + l16
    const short* gk = Kbase + (long)(wv * 16 + l16) * DOUT + quad * 8;
    // V DMA: wave wv stages e-rows 4wv+quad and +32; granule swizzle invariant
    const int erow = 4 * wv + quad;                 // 0..31
    const int cgr  = l16 ^ (erow & 15);
    const short* gv = VbaseG + (long)erow * SEQ + cgr * 8;

    f32x4 acc[4];
    #pragma unroll
    for (int e = 0; e < 4; ++e) acc[e] = (f32x4){0.f, 0.f, 0.f, 0.f};
    float mrow = -1e30f, lrow = 0.f;

    const int q_hi   = q0w + 15;
    const int qg     = q0w + l16;
    const int wfirst = wk * 32;        // wave's first key within a round
    const int R      = t / 4 + 1;      // 128-key rounds

#define STAGE_KV(B, KV0) do {                                         \
        char* kb_ = &smem[(B)][0];                                    \
        char* vb_ = &smem[(B)][0] + 16384;                            \
        const short* gkp_ = gk + (long)(KV0) * DOUT;                  \
        dma16(gkp_,      kb_ + (2 * wv) * 1024);                      \
        dma16(gkp_ + 32, kb_ + (2 * wv + 1) * 1024);                  \
        const short* gvp_ = gv + (KV0);                               \
        dma16(gvp_,            vb_ + (wv)     * 1024);                \
        dma16(gvp_ + 32 * SEQ, vb_ + (wv + 8) * 1024);                \
    } while (0)

    STAGE_KV(0, 0);
    __syncthreads();

    for (int r = 0; r < R; ++r) {
        const int kv0 = r * 128;
        const int cur = r & 1;
        if (r + 1 < R) STAGE_KV(cur ^ 1, kv0 + 128);

        if ((kv0 + wfirst) <= q_hi) {
            const char* kb = &smem[cur][0];
            const char* vb = &smem[cur][0] + 16384;

            // ---- scores^T: 32 keys (this wave's quarter) x 16 q ----
            f32x4 sc[2];
            #pragma unroll
            for (int kh = 0; kh < 2; ++kh) {
                const int slot = (wk * 2 + kh) * 2;
                bf16x8 k0 = *(const bf16x8*)(kb + slot * 1024 + lane * 16);
                bf16x8 k1 = *(const bf16x8*)(kb + (slot + 1) * 1024 + lane * 16);
                f32x4 z = (f32x4){0.f, 0.f, 0.f, 0.f};
                z = mfma16(k0, qf0, z);
                z = mfma16(k1, qf1, z);
                sc[kh] = z;
            }

            // ---- causal mask (key <= q); skip when round fully visible ----
            if (kv0 + wfirst + 31 > q0w) {
                #pragma unroll
                for (int kh = 0; kh < 2; ++kh)
                    #pragma unroll
                    for (int rr = 0; rr < 4; ++rr)
                        sc[kh][rr] = ((kv0 + wfirst + kh * 16 + quad * 4 + rr) <= qg)
                                   ? sc[kh][rr] : -1e30f;
            }

            // ---- online softmax (base 2), per-lane q ----
            float tm = fmaxf(fmaxf(fmaxf(sc[0][0], sc[0][1]), fmaxf(sc[0][2], sc[0][3])),
                             fmaxf(fmaxf(sc[1][0], sc[1][1]), fmaxf(sc[1][2], sc[1][3])));
            tm = fmaxf(tm, __shfl_xor(tm, 16, 64));
            tm = fmaxf(tm, __shfl_xor(tm, 32, 64));
            // defer-max: if no lane's max grew, alpha == exp2(0) == 1 exactly
            if (!__all(tm <= mrow)) {
                const float mn = fmaxf(mrow, tm);
                const float alpha = __builtin_amdgcn_exp2f(mrow - mn);
                mrow = mn;
                lrow *= alpha;
                #pragma unroll
                for (int e = 0; e < 4; ++e)
                    #pragma unroll
                    for (int rr = 0; rr < 4; ++rr) acc[e][rr] *= alpha;
            }
            float p[2][4];
            float rs0 = 0.f, rs1 = 0.f;
            #pragma unroll
            for (int kh = 0; kh < 2; ++kh)
                #pragma unroll
                for (int rr = 0; rr < 4; ++rr) {
                    p[kh][rr] = __builtin_amdgcn_exp2f(sc[kh][rr] - mrow);
                    if (kh == 0) rs0 += p[kh][rr]; else rs1 += p[kh][rr];
                }
            float rs = rs0 + rs1;
            rs += __shfl_xor(rs, 16, 64);
            rs += __shfl_xor(rs, 32, 64);
            lrow += rs;

            // ---- pack P (already B-frag for K=16 MFMA) ----
            union { unsigned u[2]; bf16x4 v; } pf[2];
            #pragma unroll
            for (int kh = 0; kh < 2; ++kh) {
                pf[kh].u[0] = pack_bf2(p[kh][0], p[kh][1]);
                pf[kh].u[1] = pack_bf2(p[kh][2], p[kh][3]);
            }

            // ---- O^T += V^T * P^T  (V from LDS, 16-granule swizzle) ----
            #pragma unroll
            for (int kh = 0; kh < 2; ++kh) {
                const int gbase = wk * 4 + kh * 2 + (quad >> 1);
                #pragma unroll
                for (int et = 0; et < 4; ++et) {
                    const int e = et * 16 + l16;
                    bf16x4 cv = *(const bf16x4*)(vb + e * 256
                                   + ((gbase ^ (e & 15)) * 16) + (quad & 1) * 8);
                    acc[et] = mfma16k(cv, pf[kh].v, acc[et]);
                }
            }
        }
        __syncthreads();   // publishes next buf; guards WAR on this buf
    }
#undef STAGE_KV

    // ---- epilogue: 4-way merge (wk quads); arrays alias the KV buffer ----
    float* s_m   = (float*)&smem[0][0];          // [8][16]
    float* s_l   = s_m + 128;                    // [8][16]
    float* s_acc = s_l + 128;                    // [8][16][65]

    if (quad == 0) { s_m[wv * 16 + l16] = mrow; s_l[wv * 16 + l16] = lrow; }
    #pragma unroll
    for (int et = 0; et < 4; ++et)
        #pragma unroll
        for (int rr = 0; rr < 4; ++rr)
            s_acc[(wv * 16 + l16) * 65 + et * 16 + quad * 4 + rr] = acc[et][rr];
    __syncthreads();

    const int col   = tid & 63;
    const int rbase = (tid >> 6) * 4;
    float* outp = Out + ((long)b * SEQ + t * 32) * DOUT;
    #pragma unroll
    for (int k = 0; k < 4; ++k) {
        const int row = rbase + k;               // 0..31
        const int w0  = (row >> 4) * 4;          // first wave of this q-tile
        const int lr  = row & 15;
        const float m0 = s_m[(w0 + 0) * 16 + lr];
        const float m1 = s_m[(w0 + 1) * 16 + lr];
        const float m2 = s_m[(w0 + 2) * 16 + lr];
        const float m3 = s_m[(w0 + 3) * 16 + lr];
        const float mM = fmaxf(fmaxf(m0, m1), fmaxf(m2, m3));
        const float a0 = __builtin_amdgcn_exp2f(m0 - mM);
        const float a1 = __builtin_amdgcn_exp2f(m1 - mM);
        const float a2 = __builtin_amdgcn_exp2f(m2 - mM);
        const float a3 = __builtin_amdgcn_exp2f(m3 - mM);
        const float li = a0 * s_l[(w0 + 0) * 16 + lr] + a1 * s_l[(w0 + 1) * 16 + lr]
                       + a2 * s_l[(w0 + 2) * 16 + lr] + a3 * s_l[(w0 + 3) * 16 + lr];
        const float o  = a0 * s_acc[((w0 + 0) * 16 + lr) * 65 + col]
                       + a1 * s_acc[((w0 + 1) * 16 + lr) * 65 + col]
                       + a2 * s_acc[((w0 + 2) * 16 + lr) * 65 + col]
                       + a3 * s_acc[((w0 + 3) * 16 + lr) * 65 + col];
        outp[row * DOUT + col] = o / li;
    }
}

extern "C" void kernel_launch(void* const* d_in, const int* in_sizes, int n_in,
                              void* d_out, int out_size, void* d_ws, size_t ws_size,
                              hipStream_t stream) {
    const float* key_in   = (const float*)d_in[0];
    const float* value_in = (const float*)d_in[1];
    const float* query_in = (const float*)d_in[2];
    const float* Wq = (const float*)d_in[3];
    const float* Wk = (const float*)d_in[4];
    const float* Wv = (const float*)d_in[5];
    float* out = (float*)d_out;

    short* Qb = (short*)d_ws;                          // 2 MB bf16 [B][S][64]  (pre-scaled)
    short* Kb = Qb + (long)BATCH * SEQ * DOUT;         // 2 MB bf16 [B][S][64]
    short* Vt = Kb + (long)BATCH * SEQ * DOUT;         // 2 MB bf16 [B][64][S]
    short* Wt = Vt + (long)BATCH * SEQ * DOUT;         // 192 KB bf16 [3][64][512]

    dim3 wgrid((DOUT * DIN) / 256, 3);
    wconv_kernel<<<wgrid, 256, 0, stream>>>(Wq, Wk, Wv, Wt);

    dim3 pgrid(BATCH * SEQ / 64, 3);
    proj_kernel<<<pgrid, 256, 0, stream>>>(query_in, key_in, value_in,
                                           Wt, Qb, Kb, Vt);

    flash_kernel<<<dim3(SEQ / 32 * BATCH), 512, 0, stream>>>(Qb, Kb, Vt, out);
}